// Round 18
// baseline (64.180 us; speedup 1.0000x reference)
//
#include <hip/hip_runtime.h>

#define H 256
#define SEQ 2048
#define NBATCH 64
#define M_TOTAL (NBATCH * SEQ)   // 131072 rows
#define BM 32                    // rows per tile
#define TILES 8                  // tiles per block
#define GRID (M_TOTAL / BM / TILES)  // 512 = 2 blocks/CU, one round

using bf16x8 = __attribute__((ext_vector_type(8))) short;
using f32x4  = __attribute__((ext_vector_type(4))) float;

__device__ __forceinline__ unsigned short f2bf(float x) {
    union { float f; unsigned u; } v; v.f = x;
    unsigned r = v.u + 0x7fffu + ((v.u >> 16) & 1u);   // RNE
    return (unsigned short)(r >> 16);
}

__device__ __forceinline__ bf16x8 gload16(const void* p) {
    bf16x8 r;
    asm volatile("global_load_dwordx4 %0, %1, off" : "=v"(r) : "v"(p));
    return r;
}
__device__ __forceinline__ f32x4 gloadf(const void* p) {
    f32x4 r;
    asm volatile("global_load_dwordx4 %0, %1, off" : "=v"(r) : "v"(p));
    return r;
}
__device__ __forceinline__ void gstore(void* p, float v) {
    asm volatile("global_store_dword %0, %1, off" :: "v"(p), "v"(v) : "memory");
}
#define SB0() __builtin_amdgcn_sched_barrier(0)

// ------- prep 1a: partial[g][d] = sum_{c in g-slice} q[c]*W2[c,d]  (16 blocks) -------
__global__ __launch_bounds__(256) void prep_qpb1(const float* __restrict__ q,
                                                 const float* __restrict__ W2,
                                                 float* __restrict__ partial) {
    const int g = blockIdx.x;      // 0..15
    const int t = threadIdx.x;     // d
    float s = 0.f;
#pragma unroll
    for (int i = 0; i < 16; ++i) {
        int c = g * 16 + i;
        s = fmaf(q[c], W2[c * H + t], s);
    }
    partial[g * H + t] = s;
}

// ------- prep 1b+2: blocks 0..31 pack W1 (RNE bf16); block 32 reduces qpb ------------
// W1 pack granule(ct 0..15, ks 0..7)[lane]: elem j = W1bf[ks*32+(lane>>4)*8+j][ct*16+(lane&15)]
__global__ __launch_bounds__(256) void prep_misc(const float* __restrict__ W1,
                                                 unsigned short* __restrict__ Bpack,
                                                 const float* __restrict__ partial,
                                                 const float* __restrict__ b1,
                                                 const float* __restrict__ b2,
                                                 float* __restrict__ qpb) {
    if (blockIdx.x < 32) {
        int tid = blockIdx.x * 256 + threadIdx.x;  // (ct,ks,lane)
        int ct = tid >> 9;
        int ks = (tid >> 6) & 7;
        int l  = tid & 63;
        bf16x8 hi;
#pragma unroll
        for (int j = 0; j < 8; ++j) {
            int kk = ks * 32 + ((l >> 4) & 3) * 8 + j;
            int nn = ct * 16 + (l & 15);
            hi[j] = (short)f2bf(W1[kk * H + nn]);
        }
        ((bf16x8*)Bpack)[(ct * 8 + ks) * 64 + l] = hi;
    } else {
        const int t = threadIdx.x;
        float s = b1[t] + b2[t];
#pragma unroll
        for (int g = 0; g < 16; ++g) s += partial[g * H + t];
        qpb[t] = s;
    }
}

// ---------------- main ----------------
// R16 structure (bf16-in-LDS staging, W1-in-regs, issue-early/write-late) with
// Kb padded to 2x32KB: total LDS 69.6KB -> 2 blocks/CU -> the compiler's
// occupancy target is 4 waves/EU -> 128-VGPR budget -> the 64-VGPR W1 ring
// stays register-resident. (R16/R17 at 36.9KB LDS allowed 4 blocks/CU, so the
// allocator targeted 8 waves/EU = 64-VGPR cap and SPILLED W1 - VGPR_Count=64,
// MfmaUtil 8%. LDS padding is load-bearing; do not shrink Kb.)
__global__ __launch_bounds__(512, 4) void fused_main(const float* __restrict__ kin,
                                                     const unsigned short* __restrict__ Bpack,
                                                     const float* __restrict__ qpb,
                                                     const float* __restrict__ Vp,
                                                     float* __restrict__ out_scores) {
    __shared__ __align__(16) unsigned char Kb[2][32768];   // bf16 [32][256] used; rest = occupancy pad
    __shared__ float part[2][8][32];
    __shared__ __align__(16) float qlds[256];
    __shared__ __align__(16) float vlds[256];

    const int t    = threadIdx.x;        // 0..511
    const int wave = t >> 6;             // 0..7 = n-group (32 cols)
    const int lane = t & 63;
    const int lhi  = lane >> 4;
    const int llo  = lane & 15;
    const int base = blockIdx.x * (BM * TILES);

    // qpb/V -> LDS (plain loads; drained before first barrier)
    if (t < 64)       *(f32x4*)(qlds + t * 4)        = *(const f32x4*)(qpb + t * 4);
    else if (t < 128) *(f32x4*)(vlds + (t - 64) * 4) = *(const f32x4*)(Vp + (t - 64) * 4);

    // ---- W1 -> registers, once (wave's 2 ct-slices x 8 ks = 64 VGPR) ----
    bf16x8 w1[2][8];
    const char* bb = (const char*)Bpack + (size_t)lane * 16;
#pragma unroll
    for (int c = 0; c < 2; ++c)
#pragma unroll
        for (int ks = 0; ks < 8; ++ks)
            w1[c][ks] = gload16(bb + (size_t)((wave * 2 + c) * 8 + ks) * 1024);

    // ---- pf <- tile 0 (wave loads rows i*8+wave; 64 lanes x 16B = full row) ----
    f32x4 pf[4];
#pragma unroll
    for (int i = 0; i < 4; ++i)
        pf[i] = gloadf(kin + (size_t)(base + i * 8 + wave) * H + lane * 4);

    // cvt pf -> bf16, write into Kb[B] (8B per lane per row, swizzled)
#define STAGE(B)                                                                    \
    do {                                                                            \
        _Pragma("unroll")                                                           \
        for (int i = 0; i < 4; ++i) {                                               \
            int r = i * 8 + wave;                                                   \
            unsigned c0, c1;                                                        \
            asm("v_cvt_pk_bf16_f32 %0, %1, %2" : "=v"(c0) : "v"(pf[i][0]), "v"(pf[i][1])); \
            asm("v_cvt_pk_bf16_f32 %0, %1, %2" : "=v"(c1) : "v"(pf[i][2]), "v"(pf[i][3])); \
            int addr = (r * 512 + lane * 8) ^ ((r & 7) << 4);                       \
            uint2 val; val.x = c0; val.y = c1;                                      \
            *(uint2*)(&Kb[B][addr]) = val;                                          \
        }                                                                           \
    } while (0)

    asm volatile("s_waitcnt vmcnt(0)");   // W1 + pf(tile0) landed
    SB0();
    STAGE(0);
    asm volatile("s_waitcnt lgkmcnt(0)" ::: "memory");
    __builtin_amdgcn_s_barrier();
    SB0();

#pragma unroll 1
    for (int j = 0; j < TILES; ++j) {
        const unsigned char* Kc = &Kb[j & 1][0];

        f32x4 acc[2][2];   // [ct][mt]
#pragma unroll
        for (int a = 0; a < 2; ++a)
#pragma unroll
            for (int b = 0; b < 2; ++b) acc[a][b] = (f32x4){0.f, 0.f, 0.f, 0.f};

#pragma unroll
        for (int ks = 0; ks < 8; ++ks) {
            if (ks == 0 && j < TILES - 1) {   // issue-early: next tile's rows
#pragma unroll
                for (int i = 0; i < 4; ++i)
                    pf[i] = gloadf(kin + (size_t)(base + (j + 1) * BM + i * 8 + wave) * H + lane * 4);
            }
            const int r0 = llo, r1 = 16 + llo;
            const bf16x8 kf0 = *(const bf16x8*)(Kc + ((r0 * 512 + ks * 64 + lhi * 16) ^ ((r0 & 7) << 4)));
            const bf16x8 kf1 = *(const bf16x8*)(Kc + ((r1 * 512 + ks * 64 + lhi * 16) ^ ((r1 & 7) << 4)));
            acc[0][0] = __builtin_amdgcn_mfma_f32_16x16x32_bf16(w1[0][ks], kf0, acc[0][0], 0, 0, 0);
            acc[0][1] = __builtin_amdgcn_mfma_f32_16x16x32_bf16(w1[0][ks], kf1, acc[0][1], 0, 0, 0);
            acc[1][0] = __builtin_amdgcn_mfma_f32_16x16x32_bf16(w1[1][ks], kf0, acc[1][0], 0, 0, 0);
            acc[1][1] = __builtin_amdgcn_mfma_f32_16x16x32_bf16(w1[1][ks], kf1, acc[1][1], 0, 0, 0);
        }

        // ---- epilogue: tanh, *V, in-lane reduce over wave's 32 n ----
        float sm0 = 0.f, sm1 = 0.f;
#pragma unroll
        for (int c = 0; c < 2; ++c) {
            f32x4 qv = *(const f32x4*)(qlds + wave * 32 + c * 16 + lhi * 4);
            f32x4 vv = *(const f32x4*)(vlds + wave * 32 + c * 16 + lhi * 4);
#pragma unroll
            for (int i = 0; i < 4; ++i) {
                float x0 = acc[c][0][i] + qv[i];
                float e0 = __expf(2.f * x0);
                sm0 += (1.f - 2.f * __builtin_amdgcn_rcpf(e0 + 1.f)) * vv[i];
                float x1 = acc[c][1][i] + qv[i];
                float e1 = __expf(2.f * x1);
                sm1 += (1.f - 2.f * __builtin_amdgcn_rcpf(e1 + 1.f)) * vv[i];
            }
        }
        sm0 += __shfl_xor(sm0, 16, 64); sm0 += __shfl_xor(sm0, 32, 64);
        sm1 += __shfl_xor(sm1, 16, 64); sm1 += __shfl_xor(sm1, 32, 64);
        if (lane < 16) {
            part[j & 1][wave][llo]      = sm0;
            part[j & 1][wave][16 + llo] = sm1;
        }

        // ---- write-late: cvt+stage tile j+1 (pf issued a full tile ago) ----
        if (j < TILES - 1) {
            asm volatile("s_waitcnt vmcnt(0)");
            SB0();
            STAGE((j + 1) & 1);
        }
        asm volatile("s_waitcnt lgkmcnt(0)" ::: "memory");
        __builtin_amdgcn_s_barrier();             // part + next buf visible
        SB0();

        if (t < BM) {
            float r = 0.f;
#pragma unroll
            for (int w = 0; w < 8; ++w) r += part[j & 1][w][t];
            gstore(out_scores + base + j * BM + t, r);
        }
    }
#undef STAGE
}

// ---------------- softmax over seq axis, in-place on d_out ----------------
__global__ __launch_bounds__(256) void softmax_kernel(float* __restrict__ out) {
    const int b = blockIdx.x;
    const int t = threadIdx.x;
    float* row = out + b * SEQ;
    float v[8];
#pragma unroll
    for (int j = 0; j < 8; ++j) v[j] = row[t + j * 256];
    float mx = v[0];
#pragma unroll
    for (int j = 1; j < 8; ++j) mx = fmaxf(mx, v[j]);
#pragma unroll
    for (int off = 1; off < 64; off <<= 1) mx = fmaxf(mx, __shfl_xor(mx, off, 64));
    __shared__ float redm[4], reds[4];
    int lane = t & 63, w = t >> 6;
    if (lane == 0) redm[w] = mx;
    __syncthreads();
    mx = fmaxf(fmaxf(redm[0], redm[1]), fmaxf(redm[2], redm[3]));
    float e[8], sum = 0.f;
#pragma unroll
    for (int j = 0; j < 8; ++j) { e[j] = __expf(v[j] - mx); sum += e[j]; }
#pragma unroll
    for (int off = 1; off < 64; off <<= 1) sum += __shfl_xor(sum, off, 64);
    if (lane == 0) reds[w] = sum;
    __syncthreads();
    float inv = 1.0f / (reds[0] + reds[1] + reds[2] + reds[3]);
#pragma unroll
    for (int j = 0; j < 8; ++j) row[t + j * 256] = e[j] * inv;
}

extern "C" void kernel_launch(void* const* d_in, const int* in_sizes, int n_in,
                              void* d_out, int out_size, void* d_ws, size_t ws_size,
                              hipStream_t stream) {
    const float* q  = (const float*)d_in[0];
    const float* k  = (const float*)d_in[1];
    const float* W1 = (const float*)d_in[2];
    const float* b1 = (const float*)d_in[3];
    const float* W2 = (const float*)d_in[4];
    const float* b2 = (const float*)d_in[5];
    const float* V  = (const float*)d_in[6];
    // d_in[7] = bv: softmax-invariant scalar, skipped.
    float* out = (float*)d_out;

    float* qpb     = (float*)d_ws;                                   // 1 KB
    float* partial = (float*)((char*)d_ws + 1024);                   // 16 KB
    unsigned short* Bpack = (unsigned short*)((char*)d_ws + 17408);  // 128 KB

    prep_qpb1<<<16, 256, 0, stream>>>(q, W2, partial);
    prep_misc<<<33, 256, 0, stream>>>(W1, Bpack, partial, b1, b2, qpb);
    fused_main<<<GRID, 512, 0, stream>>>(k, Bpack, qpb, V, out);
    softmax_kernel<<<NBATCH, 256, 0, stream>>>(out);
}

// Round 19
// 54.994 us; speedup vs baseline: 1.1670x; 1.1670x over previous
//
#include <hip/hip_runtime.h>

#define H 256
#define SEQ 2048
#define NBATCH 64
#define M_TOTAL (NBATCH * SEQ)   // 131072 rows
#define BM 32                    // rows per tile
#define TILES 8                  // tiles per block
#define GRID (M_TOTAL / BM / TILES)  // 512 = 2 blocks/CU, one round

using bf16x8 = __attribute__((ext_vector_type(8))) short;
using f32x4  = __attribute__((ext_vector_type(4))) float;

__device__ __forceinline__ unsigned short f2bf(float x) {
    union { float f; unsigned u; } v; v.f = x;
    unsigned r = v.u + 0x7fffu + ((v.u >> 16) & 1u);   // RNE
    return (unsigned short)(r >> 16);
}

__device__ __forceinline__ bf16x8 gload16(const void* p) {
    bf16x8 r;
    asm volatile("global_load_dwordx4 %0, %1, off" : "=v"(r) : "v"(p));
    return r;
}
__device__ __forceinline__ void gstore(void* p, float v) {
    asm volatile("global_store_dword %0, %1, off" :: "v"(p), "v"(v) : "memory");
}
__device__ __forceinline__ void gload_lds16(const void* g, void* l) {
    __builtin_amdgcn_global_load_lds(
        (const __attribute__((address_space(1))) void*)g,
        (__attribute__((address_space(3))) void*)l, 16, 0, 0);
}
#define SB0() __builtin_amdgcn_sched_barrier(0)

// ------- prep (single launch): blocks 0..31 pack W1 (RNE bf16); block 32 computes
// qpb[d] = sum_c q[c]*W2[c,d] + b1[d] + b2[d] directly (coalesced across d).
// W1 pack granule(ct 0..15, ks 0..7)[lane]: elem j = W1bf[ks*32+(lane>>4)*8+j][ct*16+(lane&15)]
__global__ __launch_bounds__(256) void prep_all(const float* __restrict__ W1,
                                                unsigned short* __restrict__ Bpack,
                                                const float* __restrict__ q,
                                                const float* __restrict__ W2,
                                                const float* __restrict__ b1,
                                                const float* __restrict__ b2,
                                                float* __restrict__ qpb) {
    if (blockIdx.x < 32) {
        int tid = blockIdx.x * 256 + threadIdx.x;  // (ct,ks,lane)
        int ct = tid >> 9;
        int ks = (tid >> 6) & 7;
        int l  = tid & 63;
        bf16x8 hi;
#pragma unroll
        for (int j = 0; j < 8; ++j) {
            int kk = ks * 32 + ((l >> 4) & 3) * 8 + j;
            int nn = ct * 16 + (l & 15);
            hi[j] = (short)f2bf(W1[kk * H + nn]);
        }
        ((bf16x8*)Bpack)[(ct * 8 + ks) * 64 + l] = hi;
    } else {
        const int t = threadIdx.x;
        float s = b1[t] + b2[t];
#pragma unroll 8
        for (int c = 0; c < H; ++c) s = fmaf(q[c], W2[c * H + t], s);
        qpb[t] = s;
    }
}

// ---------------- main (byte-identical to the R15 winner, 51.7 us) ----------------
// 512 threads = 8 waves; wave w owns n in [w*32, w*32+32), all 32 m-rows.
// W1: registers ONCE (64 VGPR) -> inner loop has ZERO global waits.
// k: f32 in LDS via global_load_lds (linear dest + pre-swizzled source),
// double-buffered; tile j+1's 4 GLDs issued at ks=0 of tile j, drained after
// the epilogue (full-tile in-flight window). Read side applies the same XOR
// and converts via v_cvt_pk_bf16_f32.
// NOTE (R16-R18 lesson): do NOT move the cvts out of the inner loop — the
// cvt-free loop trips LLVM's memory-bound perf-hint, which pins VGPR_Count=64
// and spills the w1 ring to scratch (~77us, MfmaUtil 8%). The in-loop cvts are
// load-bearing for the register allocation.
__global__ __launch_bounds__(512, 4) void fused_main(const float* __restrict__ kin,
                                                     const unsigned short* __restrict__ Bpack,
                                                     const float* __restrict__ qpb,
                                                     const float* __restrict__ Vp,
                                                     float* __restrict__ out_scores) {
    __shared__ __align__(16) unsigned char Kb[2][32768];   // f32 [32][256] x2
    __shared__ float part[2][8][32];
    __shared__ __align__(16) float qlds[256];
    __shared__ __align__(16) float vlds[256];

    const int t    = threadIdx.x;        // 0..511
    const int wave = t >> 6;             // 0..7 = n-group (32 cols)
    const int lane = t & 63;
    const int lhi  = lane >> 4;
    const int llo  = lane & 15;
    const int base = blockIdx.x * (BM * TILES);

    // qpb/V -> LDS (plain loads; compiler drains them before the ds_write)
    if (t < 64)       *(f32x4*)(qlds + t * 4)        = *(const f32x4*)(qpb + t * 4);
    else if (t < 128) *(f32x4*)(vlds + (t - 64) * 4) = *(const f32x4*)(Vp + (t - 64) * 4);

    // ---- W1 -> registers, once (wave's 2 ct-slices x 8 ks = 64 VGPR) ----
    bf16x8 w1[2][8];
    const char* bb = (const char*)Bpack + (size_t)lane * 16;
#pragma unroll
    for (int c = 0; c < 2; ++c)
#pragma unroll
        for (int ks = 0; ks < 8; ++ks)
            w1[c][ks] = gload16(bb + (size_t)((wave * 2 + c) * 8 + ks) * 1024);

    // one GLD stages one full row: row = i*8+wave (uniform), lane = 16B col.
#define STAGEG(B, TB)                                                            \
    do {                                                                         \
        _Pragma("unroll")                                                        \
        for (int i = 0; i < 4; ++i) {                                            \
            int r = i * 8 + wave;                                                \
            const float* g = kin + (size_t)((TB) + r) * H + ((lane ^ (r & 7)) << 2); \
            gload_lds16(g, &Kb[B][r * 1024]);                                    \
        }                                                                        \
    } while (0)

    STAGEG(0, base);
    asm volatile("s_waitcnt vmcnt(0)");   // W1 + tile0 staged
    SB0();
    __builtin_amdgcn_s_barrier();

#pragma unroll 1
    for (int j = 0; j < TILES; ++j) {
        const unsigned char* Kc = &Kb[j & 1][0];

        f32x4 acc[2][2];   // [ct][mt]
#pragma unroll
        for (int a = 0; a < 2; ++a)
#pragma unroll
            for (int b = 0; b < 2; ++b) acc[a][b] = (f32x4){0.f, 0.f, 0.f, 0.f};

#pragma unroll
        for (int ks = 0; ks < 8; ++ks) {
            if (ks == 0 && j < TILES - 1)
                STAGEG((j + 1) & 1, base + (j + 1) * BM);   // issue-early, drain late

            const int s0 = ks * 8 + lhi * 2;
            const int x  = llo & 7;
            const f32x4 fa0 = *(const f32x4*)(Kc + (llo     ) * 1024 + ((s0    ) ^ x) * 16);
            const f32x4 fb0 = *(const f32x4*)(Kc + (llo     ) * 1024 + ((s0 + 1) ^ x) * 16);
            const f32x4 fa1 = *(const f32x4*)(Kc + (16 + llo) * 1024 + ((s0    ) ^ x) * 16);
            const f32x4 fb1 = *(const f32x4*)(Kc + (16 + llo) * 1024 + ((s0 + 1) ^ x) * 16);
            union KU { unsigned u[4]; bf16x8 v; } k0, k1;
            asm("v_cvt_pk_bf16_f32 %0, %1, %2" : "=v"(k0.u[0]) : "v"(fa0[0]), "v"(fa0[1]));
            asm("v_cvt_pk_bf16_f32 %0, %1, %2" : "=v"(k0.u[1]) : "v"(fa0[2]), "v"(fa0[3]));
            asm("v_cvt_pk_bf16_f32 %0, %1, %2" : "=v"(k0.u[2]) : "v"(fb0[0]), "v"(fb0[1]));
            asm("v_cvt_pk_bf16_f32 %0, %1, %2" : "=v"(k0.u[3]) : "v"(fb0[2]), "v"(fb0[3]));
            asm("v_cvt_pk_bf16_f32 %0, %1, %2" : "=v"(k1.u[0]) : "v"(fa1[0]), "v"(fa1[1]));
            asm("v_cvt_pk_bf16_f32 %0, %1, %2" : "=v"(k1.u[1]) : "v"(fa1[2]), "v"(fa1[3]));
            asm("v_cvt_pk_bf16_f32 %0, %1, %2" : "=v"(k1.u[2]) : "v"(fb1[0]), "v"(fb1[1]));
            asm("v_cvt_pk_bf16_f32 %0, %1, %2" : "=v"(k1.u[3]) : "v"(fb1[2]), "v"(fb1[3]));

            acc[0][0] = __builtin_amdgcn_mfma_f32_16x16x32_bf16(w1[0][ks], k0.v, acc[0][0], 0, 0, 0);
            acc[0][1] = __builtin_amdgcn_mfma_f32_16x16x32_bf16(w1[0][ks], k1.v, acc[0][1], 0, 0, 0);
            acc[1][0] = __builtin_amdgcn_mfma_f32_16x16x32_bf16(w1[1][ks], k0.v, acc[1][0], 0, 0, 0);
            acc[1][1] = __builtin_amdgcn_mfma_f32_16x16x32_bf16(w1[1][ks], k1.v, acc[1][1], 0, 0, 0);
        }

        // ---- epilogue: tanh, *V, in-lane reduce over wave's 32 n ----
        float sm0 = 0.f, sm1 = 0.f;
#pragma unroll
        for (int c = 0; c < 2; ++c) {
            f32x4 qv = *(const f32x4*)(qlds + wave * 32 + c * 16 + lhi * 4);
            f32x4 vv = *(const f32x4*)(vlds + wave * 32 + c * 16 + lhi * 4);
#pragma unroll
            for (int i = 0; i < 4; ++i) {
                float x0 = acc[c][0][i] + qv[i];
                float e0 = __expf(2.f * x0);
                sm0 += (1.f - 2.f * __builtin_amdgcn_rcpf(e0 + 1.f)) * vv[i];
                float x1 = acc[c][1][i] + qv[i];
                float e1 = __expf(2.f * x1);
                sm1 += (1.f - 2.f * __builtin_amdgcn_rcpf(e1 + 1.f)) * vv[i];
            }
        }
        sm0 += __shfl_xor(sm0, 16, 64); sm0 += __shfl_xor(sm0, 32, 64);
        sm1 += __shfl_xor(sm1, 16, 64); sm1 += __shfl_xor(sm1, 32, 64);
        if (lane < 16) {
            part[j & 1][wave][llo]      = sm0;
            part[j & 1][wave][16 + llo] = sm1;
        }

        // drain tile j+1's GLDs (issued a full tile ago) + prior store; swap
        asm volatile("s_waitcnt vmcnt(0)");
        asm volatile("s_waitcnt lgkmcnt(0)" ::: "memory");
        __builtin_amdgcn_s_barrier();
        SB0();

        if (t < BM) {
            float r = 0.f;
#pragma unroll
            for (int w = 0; w < 8; ++w) r += part[j & 1][w][t];
            gstore(out_scores + base + j * BM + t, r);
        }
    }
#undef STAGEG
}

// ---------------- softmax over seq axis, in-place on d_out ----------------
__global__ __launch_bounds__(256) void softmax_kernel(float* __restrict__ out) {
    const int b = blockIdx.x;
    const int t = threadIdx.x;
    float* row = out + b * SEQ;
    float v[8];
#pragma unroll
    for (int j = 0; j < 8; ++j) v[j] = row[t + j * 256];
    float mx = v[0];
#pragma unroll
    for (int j = 1; j < 8; ++j) mx = fmaxf(mx, v[j]);
#pragma unroll
    for (int off = 1; off < 64; off <<= 1) mx = fmaxf(mx, __shfl_xor(mx, off, 64));
    __shared__ float redm[4], reds[4];
    int lane = t & 63, w = t >> 6;
    if (lane == 0) redm[w] = mx;
    __syncthreads();
    mx = fmaxf(fmaxf(redm[0], redm[1]), fmaxf(redm[2], redm[3]));
    float e[8], sum = 0.f;
#pragma unroll
    for (int j = 0; j < 8; ++j) { e[j] = __expf(v[j] - mx); sum += e[j]; }
#pragma unroll
    for (int off = 1; off < 64; off <<= 1) sum += __shfl_xor(sum, off, 64);
    if (lane == 0) reds[w] = sum;
    __syncthreads();
    float inv = 1.0f / (reds[0] + reds[1] + reds[2] + reds[3]);
#pragma unroll
    for (int j = 0; j < 8; ++j) row[t + j * 256] = e[j] * inv;
}

extern "C" void kernel_launch(void* const* d_in, const int* in_sizes, int n_in,
                              void* d_out, int out_size, void* d_ws, size_t ws_size,
                              hipStream_t stream) {
    const float* q  = (const float*)d_in[0];
    const float* k  = (const float*)d_in[1];
    const float* W1 = (const float*)d_in[2];
    const float* b1 = (const float*)d_in[3];
    const float* W2 = (const float*)d_in[4];
    const float* b2 = (const float*)d_in[5];
    const float* V  = (const float*)d_in[6];
    // d_in[7] = bv: softmax-invariant scalar, skipped.
    float* out = (float*)d_out;

    float* qpb = (float*)d_ws;                                     // 1 KB
    unsigned short* Bpack = (unsigned short*)((char*)d_ws + 1024); // 128 KB

    prep_all<<<33, 256, 0, stream>>>(W1, Bpack, q, W2, b1, b2, qpb);
    fused_main<<<GRID, 512, 0, stream>>>(k, Bpack, qpb, V, out);
    softmax_kernel<<<NBATCH, 256, 0, stream>>>(out);
}

// Round 20
// 51.719 us; speedup vs baseline: 1.2409x; 1.0633x over previous
//
#include <hip/hip_runtime.h>

#define H 256
#define SEQ 2048
#define NBATCH 64
#define M_TOTAL (NBATCH * SEQ)   // 131072 rows
#define BM 32                    // rows per tile
#define TILES 8                  // tiles per block
#define GRID (M_TOTAL / BM / TILES)  // 512 = 2 blocks/CU, one round

using bf16x8 = __attribute__((ext_vector_type(8))) short;
using f32x4  = __attribute__((ext_vector_type(4))) float;

__device__ __forceinline__ unsigned short f2bf(float x) {
    union { float f; unsigned u; } v; v.f = x;
    unsigned r = v.u + 0x7fffu + ((v.u >> 16) & 1u);   // RNE
    return (unsigned short)(r >> 16);
}

__device__ __forceinline__ bf16x8 gload16(const void* p) {
    bf16x8 r;
    asm volatile("global_load_dwordx4 %0, %1, off" : "=v"(r) : "v"(p));
    return r;
}
__device__ __forceinline__ void gstore(void* p, float v) {
    asm volatile("global_store_dword %0, %1, off" :: "v"(p), "v"(v) : "memory");
}
__device__ __forceinline__ void gload_lds16(const void* g, void* l) {
    __builtin_amdgcn_global_load_lds(
        (const __attribute__((address_space(1))) void*)g,
        (__attribute__((address_space(3))) void*)l, 16, 0, 0);
}
#define SB0() __builtin_amdgcn_sched_barrier(0)

// ------- prep 1a: partial[g][d] = sum_{c in g-slice} q[c]*W2[c,d]  (16 blocks) -------
// Parallel form is load-bearing: the single-block serial qpb loop (R19) is a
// ~4us latency chain that gates fused_main (+3.3us whole-bench regression).
__global__ __launch_bounds__(256) void prep_qpb1(const float* __restrict__ q,
                                                 const float* __restrict__ W2,
                                                 float* __restrict__ partial) {
    const int g = blockIdx.x;      // 0..15
    const int t = threadIdx.x;     // d
    float s = 0.f;
#pragma unroll
    for (int i = 0; i < 16; ++i) {
        int c = g * 16 + i;
        s = fmaf(q[c], W2[c * H + t], s);
    }
    partial[g * H + t] = s;
}

// ------- prep 1b+2: blocks 0..31 pack W1 (RNE bf16); block 32 reduces qpb ------------
// W1 pack granule(ct 0..15, ks 0..7)[lane]: elem j = W1bf[ks*32+(lane>>4)*8+j][ct*16+(lane&15)]
__global__ __launch_bounds__(256) void prep_misc(const float* __restrict__ W1,
                                                 unsigned short* __restrict__ Bpack,
                                                 const float* __restrict__ partial,
                                                 const float* __restrict__ b1,
                                                 const float* __restrict__ b2,
                                                 float* __restrict__ qpb) {
    if (blockIdx.x < 32) {
        int tid = blockIdx.x * 256 + threadIdx.x;  // (ct,ks,lane)
        int ct = tid >> 9;
        int ks = (tid >> 6) & 7;
        int l  = tid & 63;
        bf16x8 hi;
#pragma unroll
        for (int j = 0; j < 8; ++j) {
            int kk = ks * 32 + ((l >> 4) & 3) * 8 + j;
            int nn = ct * 16 + (l & 15);
            hi[j] = (short)f2bf(W1[kk * H + nn]);
        }
        ((bf16x8*)Bpack)[(ct * 8 + ks) * 64 + l] = hi;
    } else {
        const int t = threadIdx.x;
        float s = b1[t] + b2[t];
#pragma unroll
        for (int g = 0; g < 16; ++g) s += partial[g * H + t];
        qpb[t] = s;
    }
}

// ---------------- main (byte-identical to the R15 winner, 51.7 us) ----------------
// 512 threads = 8 waves; wave w owns n in [w*32, w*32+32), all 32 m-rows.
// W1: registers ONCE (64 VGPR) -> inner loop has ZERO global waits.
// k: f32 in LDS via global_load_lds (linear dest + pre-swizzled source),
// double-buffered; tile j+1's 4 GLDs issued at ks=0 of tile j, drained after
// the epilogue (full-tile in-flight window). Read side applies the same XOR
// and converts via v_cvt_pk_bf16_f32.
// NOTE (R14/R16-R18 lesson): do NOT move the cvts out of the inner loop and do
// NOT reg-stage k — both variants trip the register allocator into a 64-VGPR
// allocation that spills the w1 ring to scratch (VGPR_Count=64, FETCH +19MB,
// MfmaUtil 8%, ~77us). launch_bounds/waves_per_eu/LDS-padding do not override
// it. The in-loop cvts are load-bearing for the register allocation.
__global__ __launch_bounds__(512, 4) void fused_main(const float* __restrict__ kin,
                                                     const unsigned short* __restrict__ Bpack,
                                                     const float* __restrict__ qpb,
                                                     const float* __restrict__ Vp,
                                                     float* __restrict__ out_scores) {
    __shared__ __align__(16) unsigned char Kb[2][32768];   // f32 [32][256] x2
    __shared__ float part[2][8][32];
    __shared__ __align__(16) float qlds[256];
    __shared__ __align__(16) float vlds[256];

    const int t    = threadIdx.x;        // 0..511
    const int wave = t >> 6;             // 0..7 = n-group (32 cols)
    const int lane = t & 63;
    const int lhi  = lane >> 4;
    const int llo  = lane & 15;
    const int base = blockIdx.x * (BM * TILES);

    // qpb/V -> LDS (plain loads; compiler drains them before the ds_write)
    if (t < 64)       *(f32x4*)(qlds + t * 4)        = *(const f32x4*)(qpb + t * 4);
    else if (t < 128) *(f32x4*)(vlds + (t - 64) * 4) = *(const f32x4*)(Vp + (t - 64) * 4);

    // ---- W1 -> registers, once (wave's 2 ct-slices x 8 ks = 64 VGPR) ----
    bf16x8 w1[2][8];
    const char* bb = (const char*)Bpack + (size_t)lane * 16;
#pragma unroll
    for (int c = 0; c < 2; ++c)
#pragma unroll
        for (int ks = 0; ks < 8; ++ks)
            w1[c][ks] = gload16(bb + (size_t)((wave * 2 + c) * 8 + ks) * 1024);

    // one GLD stages one full row: row = i*8+wave (uniform), lane = 16B col.
#define STAGEG(B, TB)                                                            \
    do {                                                                         \
        _Pragma("unroll")                                                        \
        for (int i = 0; i < 4; ++i) {                                            \
            int r = i * 8 + wave;                                                \
            const float* g = kin + (size_t)((TB) + r) * H + ((lane ^ (r & 7)) << 2); \
            gload_lds16(g, &Kb[B][r * 1024]);                                    \
        }                                                                        \
    } while (0)

    STAGEG(0, base);
    asm volatile("s_waitcnt vmcnt(0)");   // W1 + tile0 staged
    SB0();
    __builtin_amdgcn_s_barrier();

#pragma unroll 1
    for (int j = 0; j < TILES; ++j) {
        const unsigned char* Kc = &Kb[j & 1][0];

        f32x4 acc[2][2];   // [ct][mt]
#pragma unroll
        for (int a = 0; a < 2; ++a)
#pragma unroll
            for (int b = 0; b < 2; ++b) acc[a][b] = (f32x4){0.f, 0.f, 0.f, 0.f};

#pragma unroll
        for (int ks = 0; ks < 8; ++ks) {
            if (ks == 0 && j < TILES - 1)
                STAGEG((j + 1) & 1, base + (j + 1) * BM);   // issue-early, drain late

            const int s0 = ks * 8 + lhi * 2;
            const int x  = llo & 7;
            const f32x4 fa0 = *(const f32x4*)(Kc + (llo     ) * 1024 + ((s0    ) ^ x) * 16);
            const f32x4 fb0 = *(const f32x4*)(Kc + (llo     ) * 1024 + ((s0 + 1) ^ x) * 16);
            const f32x4 fa1 = *(const f32x4*)(Kc + (16 + llo) * 1024 + ((s0    ) ^ x) * 16);
            const f32x4 fb1 = *(const f32x4*)(Kc + (16 + llo) * 1024 + ((s0 + 1) ^ x) * 16);
            union KU { unsigned u[4]; bf16x8 v; } k0, k1;
            asm("v_cvt_pk_bf16_f32 %0, %1, %2" : "=v"(k0.u[0]) : "v"(fa0[0]), "v"(fa0[1]));
            asm("v_cvt_pk_bf16_f32 %0, %1, %2" : "=v"(k0.u[1]) : "v"(fa0[2]), "v"(fa0[3]));
            asm("v_cvt_pk_bf16_f32 %0, %1, %2" : "=v"(k0.u[2]) : "v"(fb0[0]), "v"(fb0[1]));
            asm("v_cvt_pk_bf16_f32 %0, %1, %2" : "=v"(k0.u[3]) : "v"(fb0[2]), "v"(fb0[3]));
            asm("v_cvt_pk_bf16_f32 %0, %1, %2" : "=v"(k1.u[0]) : "v"(fa1[0]), "v"(fa1[1]));
            asm("v_cvt_pk_bf16_f32 %0, %1, %2" : "=v"(k1.u[1]) : "v"(fa1[2]), "v"(fa1[3]));
            asm("v_cvt_pk_bf16_f32 %0, %1, %2" : "=v"(k1.u[2]) : "v"(fb1[0]), "v"(fb1[1]));
            asm("v_cvt_pk_bf16_f32 %0, %1, %2" : "=v"(k1.u[3]) : "v"(fb1[2]), "v"(fb1[3]));

            acc[0][0] = __builtin_amdgcn_mfma_f32_16x16x32_bf16(w1[0][ks], k0.v, acc[0][0], 0, 0, 0);
            acc[0][1] = __builtin_amdgcn_mfma_f32_16x16x32_bf16(w1[0][ks], k1.v, acc[0][1], 0, 0, 0);
            acc[1][0] = __builtin_amdgcn_mfma_f32_16x16x32_bf16(w1[1][ks], k0.v, acc[1][0], 0, 0, 0);
            acc[1][1] = __builtin_amdgcn_mfma_f32_16x16x32_bf16(w1[1][ks], k1.v, acc[1][1], 0, 0, 0);
        }

        // ---- epilogue: tanh, *V, in-lane reduce over wave's 32 n ----
        float sm0 = 0.f, sm1 = 0.f;
#pragma unroll
        for (int c = 0; c < 2; ++c) {
            f32x4 qv = *(const f32x4*)(qlds + wave * 32 + c * 16 + lhi * 4);
            f32x4 vv = *(const f32x4*)(vlds + wave * 32 + c * 16 + lhi * 4);
#pragma unroll
            for (int i = 0; i < 4; ++i) {
                float x0 = acc[c][0][i] + qv[i];
                float e0 = __expf(2.f * x0);
                sm0 += (1.f - 2.f * __builtin_amdgcn_rcpf(e0 + 1.f)) * vv[i];
                float x1 = acc[c][1][i] + qv[i];
                float e1 = __expf(2.f * x1);
                sm1 += (1.f - 2.f * __builtin_amdgcn_rcpf(e1 + 1.f)) * vv[i];
            }
        }
        sm0 += __shfl_xor(sm0, 16, 64); sm0 += __shfl_xor(sm0, 32, 64);
        sm1 += __shfl_xor(sm1, 16, 64); sm1 += __shfl_xor(sm1, 32, 64);
        if (lane < 16) {
            part[j & 1][wave][llo]      = sm0;
            part[j & 1][wave][16 + llo] = sm1;
        }

        // drain tile j+1's GLDs (issued a full tile ago) + prior store; swap
        asm volatile("s_waitcnt vmcnt(0)");
        asm volatile("s_waitcnt lgkmcnt(0)" ::: "memory");
        __builtin_amdgcn_s_barrier();
        SB0();

        if (t < BM) {
            float r = 0.f;
#pragma unroll
            for (int w = 0; w < 8; ++w) r += part[j & 1][w][t];
            gstore(out_scores + base + j * BM + t, r);
        }
    }
#undef STAGEG
}

// ---------------- softmax over seq axis, in-place on d_out ----------------
__global__ __launch_bounds__(256) void softmax_kernel(float* __restrict__ out) {
    const int b = blockIdx.x;
    const int t = threadIdx.x;
    float* row = out + b * SEQ;
    float v[8];
#pragma unroll
    for (int j = 0; j < 8; ++j) v[j] = row[t + j * 256];
    float mx = v[0];
#pragma unroll
    for (int j = 1; j < 8; ++j) mx = fmaxf(mx, v[j]);
#pragma unroll
    for (int off = 1; off < 64; off <<= 1) mx = fmaxf(mx, __shfl_xor(mx, off, 64));
    __shared__ float redm[4], reds[4];
    int lane = t & 63, w = t >> 6;
    if (lane == 0) redm[w] = mx;
    __syncthreads();
    mx = fmaxf(fmaxf(redm[0], redm[1]), fmaxf(redm[2], redm[3]));
    float e[8], sum = 0.f;
#pragma unroll
    for (int j = 0; j < 8; ++j) { e[j] = __expf(v[j] - mx); sum += e[j]; }
#pragma unroll
    for (int off = 1; off < 64; off <<= 1) sum += __shfl_xor(sum, off, 64);
    if (lane == 0) reds[w] = sum;
    __syncthreads();
    float inv = 1.0f / (reds[0] + reds[1] + reds[2] + reds[3]);
#pragma unroll
    for (int j = 0; j < 8; ++j) row[t + j * 256] = e[j] * inv;
}

extern "C" void kernel_launch(void* const* d_in, const int* in_sizes, int n_in,
                              void* d_out, int out_size, void* d_ws, size_t ws_size,
                              hipStream_t stream) {
    const float* q  = (const float*)d_in[0];
    const float* k  = (const float*)d_in[1];
    const float* W1 = (const float*)d_in[2];
    const float* b1 = (const float*)d_in[3];
    const float* W2 = (const float*)d_in[4];
    const float* b2 = (const float*)d_in[5];
    const float* V  = (const float*)d_in[6];
    // d_in[7] = bv: softmax-invariant scalar, skipped.
    float* out = (float*)d_out;

    float* qpb     = (float*)d_ws;                                   // 1 KB
    float* partial = (float*)((char*)d_ws + 1024);                   // 16 KB
    unsigned short* Bpack = (unsigned short*)((char*)d_ws + 17408);  // 128 KB

    prep_qpb1<<<16, 256, 0, stream>>>(q, W2, partial);
    prep_misc<<<33, 256, 0, stream>>>(W1, Bpack, partial, b1, b2, qpb);
    fused_main<<<GRID, 512, 0, stream>>>(k, Bpack, qpb, V, out);
    softmax_kernel<<<NBATCH, 256, 0, stream>>>(out);
}

// Round 21
// 46.098 us; speedup vs baseline: 1.3923x; 1.1219x over previous
//
#include <hip/hip_runtime.h>

#define H 256
#define SEQ 2048
#define NBATCH 64
#define M_TOTAL (NBATCH * SEQ)   // 131072 rows
#define BM 32                    // rows per tile
#define TILES 8                  // tiles per block
#define GRID (M_TOTAL / BM / TILES)  // 512 = 2 blocks/CU, one round

using bf16x8 = __attribute__((ext_vector_type(8))) short;
using f32x4  = __attribute__((ext_vector_type(4))) float;

__device__ __forceinline__ unsigned short f2bf(float x) {
    union { float f; unsigned u; } v; v.f = x;
    unsigned r = v.u + 0x7fffu + ((v.u >> 16) & 1u);   // RNE
    return (unsigned short)(r >> 16);
}

__device__ __forceinline__ bf16x8 gload16(const void* p) {
    bf16x8 r;
    asm volatile("global_load_dwordx4 %0, %1, off" : "=v"(r) : "v"(p));
    return r;
}
__device__ __forceinline__ void gstore(void* p, float v) {
    asm volatile("global_store_dword %0, %1, off" :: "v"(p), "v"(v) : "memory");
}
__device__ __forceinline__ void gload_lds16(const void* g, void* l) {
    __builtin_amdgcn_global_load_lds(
        (const __attribute__((address_space(1))) void*)g,
        (__attribute__((address_space(3))) void*)l, 16, 0, 0);
}
#define SB0() __builtin_amdgcn_sched_barrier(0)

// ------- prep 1a: partial[g][d] = sum_{c in g-slice} q[c]*W2[c,d]  (16 blocks) -------
// Parallel form is load-bearing: a single-block serial qpb loop (R19) is a ~4us
// latency chain that gates fused_main.
__global__ __launch_bounds__(256) void prep_qpb1(const float* __restrict__ q,
                                                 const float* __restrict__ W2,
                                                 float* __restrict__ partial) {
    const int g = blockIdx.x;      // 0..15
    const int t = threadIdx.x;     // d
    float s = 0.f;
#pragma unroll
    for (int i = 0; i < 16; ++i) {
        int c = g * 16 + i;
        s = fmaf(q[c], W2[c * H + t], s);
    }
    partial[g * H + t] = s;
}

// ------- prep 1b+2: blocks 0..31 pack W1 (RNE bf16); block 32 reduces qpb ------------
// W1 pack granule(ct 0..15, ks 0..7)[lane]: elem j = W1bf[ks*32+(lane>>4)*8+j][ct*16+(lane&15)]
__global__ __launch_bounds__(256) void prep_misc(const float* __restrict__ W1,
                                                 unsigned short* __restrict__ Bpack,
                                                 const float* __restrict__ partial,
                                                 const float* __restrict__ b1,
                                                 const float* __restrict__ b2,
                                                 float* __restrict__ qpb) {
    if (blockIdx.x < 32) {
        int tid = blockIdx.x * 256 + threadIdx.x;  // (ct,ks,lane)
        int ct = tid >> 9;
        int ks = (tid >> 6) & 7;
        int l  = tid & 63;
        bf16x8 hi;
#pragma unroll
        for (int j = 0; j < 8; ++j) {
            int kk = ks * 32 + ((l >> 4) & 3) * 8 + j;
            int nn = ct * 16 + (l & 15);
            hi[j] = (short)f2bf(W1[kk * H + nn]);
        }
        ((bf16x8*)Bpack)[(ct * 8 + ks) * 64 + l] = hi;
    } else {
        const int t = threadIdx.x;
        float s = b1[t] + b2[t];
#pragma unroll
        for (int g = 0; g < 16; ++g) s += partial[g * H + t];
        qpb[t] = s;
    }
}

// ---------------- main ----------------
// n-split 4: 256 threads = 4 waves; wave w owns n in [w*64, w*64+64) (4 ct), all
// 32 m-rows. All waves read IDENTICAL k-fragments, so halving the wave count
// halves total LDS-read traffic (the R15 structure's binding cost). W1 slice
// doubles to 128 VGPR -> needs the 256-VGPR budget at 2 waves/EU:
// __launch_bounds__(256, 2). In-loop cvt structure preserved (R14/R16-R18:
// cvt-free loops trip the allocator into a 64-VGPR spill of w1; the cvts are
// load-bearing). k: f32 via global_load_lds, double-buffered, issue-early at
// ks=0 / drain-late after epilogue. Swizzle ^(r&7) on 16B slots, both sides.
__global__ __launch_bounds__(256, 2) void fused_main(const float* __restrict__ kin,
                                                     const unsigned short* __restrict__ Bpack,
                                                     const float* __restrict__ qpb,
                                                     const float* __restrict__ Vp,
                                                     float* __restrict__ out_scores) {
    __shared__ __align__(16) unsigned char Kb[2][32768];   // f32 [32][256] x2
    __shared__ float part[2][4][32];
    __shared__ __align__(16) float qlds[256];
    __shared__ __align__(16) float vlds[256];

    const int t    = threadIdx.x;        // 0..255
    const int wave = t >> 6;             // 0..3 = n-group (64 cols)
    const int lane = t & 63;
    const int lhi  = lane >> 4;
    const int llo  = lane & 15;
    const int base = blockIdx.x * (BM * TILES);

    // qpb/V -> LDS (plain loads; compiler drains them before first barrier)
    if (t < 64)       *(f32x4*)(qlds + t * 4)        = *(const f32x4*)(qpb + t * 4);
    else if (t < 128) *(f32x4*)(vlds + (t - 64) * 4) = *(const f32x4*)(Vp + (t - 64) * 4);

    // ---- W1 -> registers, once (wave's 4 ct-slices x 8 ks = 128 VGPR) ----
    bf16x8 w1[4][8];
    const char* bb = (const char*)Bpack + (size_t)lane * 16;
#pragma unroll
    for (int c = 0; c < 4; ++c)
#pragma unroll
        for (int ks = 0; ks < 8; ++ks)
            w1[c][ks] = gload16(bb + (size_t)((wave * 4 + c) * 8 + ks) * 1024);

    // one GLD stages one full row: row = i*4+wave (uniform), lane = 16B col.
#define STAGEG(B, TB)                                                            \
    do {                                                                         \
        _Pragma("unroll")                                                        \
        for (int i = 0; i < 8; ++i) {                                            \
            int r = i * 4 + wave;                                                \
            const float* g = kin + (size_t)((TB) + r) * H + ((lane ^ (r & 7)) << 2); \
            gload_lds16(g, &Kb[B][r * 1024]);                                    \
        }                                                                        \
    } while (0)

    STAGEG(0, base);
    asm volatile("s_waitcnt vmcnt(0)");   // W1 + tile0 staged
    SB0();
    __builtin_amdgcn_s_barrier();

#pragma unroll 1
    for (int j = 0; j < TILES; ++j) {
        const unsigned char* Kc = &Kb[j & 1][0];

        f32x4 acc[4][2];   // [ct][mt]
#pragma unroll
        for (int a = 0; a < 4; ++a)
#pragma unroll
            for (int b = 0; b < 2; ++b) acc[a][b] = (f32x4){0.f, 0.f, 0.f, 0.f};

#pragma unroll
        for (int ks = 0; ks < 8; ++ks) {
            if (ks == 0 && j < TILES - 1)
                STAGEG((j + 1) & 1, base + (j + 1) * BM);   // issue-early, drain late

            const int s0 = ks * 8 + lhi * 2;
            const int x  = llo & 7;
            const f32x4 fa0 = *(const f32x4*)(Kc + (llo     ) * 1024 + ((s0    ) ^ x) * 16);
            const f32x4 fb0 = *(const f32x4*)(Kc + (llo     ) * 1024 + ((s0 + 1) ^ x) * 16);
            const f32x4 fa1 = *(const f32x4*)(Kc + (16 + llo) * 1024 + ((s0    ) ^ x) * 16);
            const f32x4 fb1 = *(const f32x4*)(Kc + (16 + llo) * 1024 + ((s0 + 1) ^ x) * 16);
            union KU { unsigned u[4]; bf16x8 v; } k0, k1;
            asm("v_cvt_pk_bf16_f32 %0, %1, %2" : "=v"(k0.u[0]) : "v"(fa0[0]), "v"(fa0[1]));
            asm("v_cvt_pk_bf16_f32 %0, %1, %2" : "=v"(k0.u[1]) : "v"(fa0[2]), "v"(fa0[3]));
            asm("v_cvt_pk_bf16_f32 %0, %1, %2" : "=v"(k0.u[2]) : "v"(fb0[0]), "v"(fb0[1]));
            asm("v_cvt_pk_bf16_f32 %0, %1, %2" : "=v"(k0.u[3]) : "v"(fb0[2]), "v"(fb0[3]));
            asm("v_cvt_pk_bf16_f32 %0, %1, %2" : "=v"(k1.u[0]) : "v"(fa1[0]), "v"(fa1[1]));
            asm("v_cvt_pk_bf16_f32 %0, %1, %2" : "=v"(k1.u[1]) : "v"(fa1[2]), "v"(fa1[3]));
            asm("v_cvt_pk_bf16_f32 %0, %1, %2" : "=v"(k1.u[2]) : "v"(fb1[0]), "v"(fb1[1]));
            asm("v_cvt_pk_bf16_f32 %0, %1, %2" : "=v"(k1.u[3]) : "v"(fb1[2]), "v"(fb1[3]));

#pragma unroll
            for (int c = 0; c < 4; ++c) {
                acc[c][0] = __builtin_amdgcn_mfma_f32_16x16x32_bf16(w1[c][ks], k0.v, acc[c][0], 0, 0, 0);
                acc[c][1] = __builtin_amdgcn_mfma_f32_16x16x32_bf16(w1[c][ks], k1.v, acc[c][1], 0, 0, 0);
            }
        }

        // ---- epilogue: tanh, *V, in-lane reduce over wave's 64 n ----
        float sm0 = 0.f, sm1 = 0.f;
#pragma unroll
        for (int c = 0; c < 4; ++c) {
            f32x4 qv = *(const f32x4*)(qlds + wave * 64 + c * 16 + lhi * 4);
            f32x4 vv = *(const f32x4*)(vlds + wave * 64 + c * 16 + lhi * 4);
#pragma unroll
            for (int i = 0; i < 4; ++i) {
                float x0 = acc[c][0][i] + qv[i];
                float e0 = __expf(2.f * x0);
                sm0 += (1.f - 2.f * __builtin_amdgcn_rcpf(e0 + 1.f)) * vv[i];
                float x1 = acc[c][1][i] + qv[i];
                float e1 = __expf(2.f * x1);
                sm1 += (1.f - 2.f * __builtin_amdgcn_rcpf(e1 + 1.f)) * vv[i];
            }
        }
        sm0 += __shfl_xor(sm0, 16, 64); sm0 += __shfl_xor(sm0, 32, 64);
        sm1 += __shfl_xor(sm1, 16, 64); sm1 += __shfl_xor(sm1, 32, 64);
        if (lane < 16) {
            part[j & 1][wave][llo]      = sm0;
            part[j & 1][wave][16 + llo] = sm1;
        }

        // drain tile j+1's GLDs (issued a full tile ago) + prior store; swap
        asm volatile("s_waitcnt vmcnt(0)");
        asm volatile("s_waitcnt lgkmcnt(0)" ::: "memory");
        __builtin_amdgcn_s_barrier();
        SB0();

        if (t < BM) {
            float r = part[j & 1][0][t] + part[j & 1][1][t]
                    + part[j & 1][2][t] + part[j & 1][3][t];
            gstore(out_scores + base + j * BM + t, r);
        }
    }
#undef STAGEG
}

// ---------------- softmax over seq axis, in-place on d_out ----------------
__global__ __launch_bounds__(256) void softmax_kernel(float* __restrict__ out) {
    const int b = blockIdx.x;
    const int t = threadIdx.x;
    float* row = out + b * SEQ;
    float v[8];
#pragma unroll
    for (int j = 0; j < 8; ++j) v[j] = row[t + j * 256];
    float mx = v[0];
#pragma unroll
    for (int j = 1; j < 8; ++j) mx = fmaxf(mx, v[j]);
#pragma unroll
    for (int off = 1; off < 64; off <<= 1) mx = fmaxf(mx, __shfl_xor(mx, off, 64));
    __shared__ float redm[4], reds[4];
    int lane = t & 63, w = t >> 6;
    if (lane == 0) redm[w] = mx;
    __syncthreads();
    mx = fmaxf(fmaxf(redm[0], redm[1]), fmaxf(redm[2], redm[3]));
    float e[8], sum = 0.f;
#pragma unroll
    for (int j = 0; j < 8; ++j) { e[j] = __expf(v[j] - mx); sum += e[j]; }
#pragma unroll
    for (int off = 1; off < 64; off <<= 1) sum += __shfl_xor(sum, off, 64);
    if (lane == 0) reds[w] = sum;
    __syncthreads();
    float inv = 1.0f / (reds[0] + reds[1] + reds[2] + reds[3]);
#pragma unroll
    for (int j = 0; j < 8; ++j) row[t + j * 256] = e[j] * inv;
}

extern "C" void kernel_launch(void* const* d_in, const int* in_sizes, int n_in,
                              void* d_out, int out_size, void* d_ws, size_t ws_size,
                              hipStream_t stream) {
    const float* q  = (const float*)d_in[0];
    const float* k  = (const float*)d_in[1];
    const float* W1 = (const float*)d_in[2];
    const float* b1 = (const float*)d_in[3];
    const float* W2 = (const float*)d_in[4];
    const float* b2 = (const float*)d_in[5];
    const float* V  = (const float*)d_in[6];
    // d_in[7] = bv: softmax-invariant scalar, skipped.
    float* out = (float*)d_out;

    float* qpb     = (float*)d_ws;                                   // 1 KB
    float* partial = (float*)((char*)d_ws + 1024);                   // 16 KB
    unsigned short* Bpack = (unsigned short*)((char*)d_ws + 17408);  // 128 KB

    prep_qpb1<<<16, 256, 0, stream>>>(q, W2, partial);
    prep_misc<<<33, 256, 0, stream>>>(W1, Bpack, partial, b1, b2, qpb);
    fused_main<<<GRID, 256, 0, stream>>>(k, Bpack, qpb, V, out);
    softmax_kernel<<<NBATCH, 256, 0, stream>>>(out);
}